// Round 1
// baseline (243.209 us; speedup 1.0000x reference)
//
#include <hip/hip_runtime.h>

// SegmentLUT: piecewise-linear fixed-point op on qint16-quantized input.
//   xi  = clip(rint(x / input_scale), -32768, 32767)            (int32)
//   idx = #{ j : segment_max[j] < xi }   (searchsorted left, clipped to 7)
//   acc = alpha[idx]*xi + (beta[idx] << ls[idx]) + rbias[idx]
//   qy  = clip(acc >> rs[idx], -32768, 32767)
//   y   = float(qy) * out_scale
// Memory-bound: 128 MiB in + 128 MiB out.

#define SEG_I16_MIN (-32768)
#define SEG_I16_MAX (32767)

__device__ __forceinline__ float seg_one(float x, float s, float os,
                                         int sm0, int sm1, int sm2, int sm3,
                                         int sm4, int sm5, int sm6,
                                         const int4* tab)
{
    float xf = x / s;                 // IEEE-exact division (matches np)
    xf = rintf(xf);                   // round half-to-even (matches np.round)
    xf = fminf(fmaxf(xf, -32768.0f), 32767.0f);
    int xi = (int)xf;
    // searchsorted(side='left'): count strictly-less upper bounds.
    // segment_max[7] == 32767 >= xi always, so j=0..6 suffices (idx in 0..7).
    int idx = (sm0 < xi) + (sm1 < xi) + (sm2 < xi) + (sm3 < xi)
            + (sm4 < xi) + (sm5 < xi) + (sm6 < xi);
    int4 t = tab[idx];                // one ds_read_b128, conflict-free
    int acc = t.x * xi + t.y;         // alpha*xi + ((b<<ls)+rbias)
    int qy = acc >> t.z;              // arithmetic shift by rs
    qy = min(max(qy, SEG_I16_MIN), SEG_I16_MAX);
    return (float)qy * os;
}

__global__ __launch_bounds__(256) void SegmentLUT_83021717831949_kernel(
    const float* __restrict__ x,
    const float* __restrict__ input_scale,
    const float* __restrict__ out_scale,
    const int*   __restrict__ alpha,
    const int*   __restrict__ beta,
    const int*   __restrict__ lsh,
    const int*   __restrict__ rsh,
    const int*   __restrict__ smax,
    float*       __restrict__ out,
    int n)                                    // total elements
{
    __shared__ int4 tab[8];  // {alpha, (beta<<ls)+rbias, rs, 0} per segment
    if (threadIdx.x < 8) {
        int j  = (int)threadIdx.x;
        int rs = rsh[j];
        int rm1 = rs - 1 > 0 ? rs - 1 : 0;
        int rbias = rs > 0 ? (1 << rm1) : 0;
        int bc = (int)((unsigned)beta[j] << (lsh[j] & 31)) + rbias;
        tab[j] = make_int4(alpha[j], bc, rs, 0);
    }
    // Uniform scalars / small table into registers (scalarized by compiler).
    float s  = input_scale[0];
    float os = out_scale[0];
    int sm0 = smax[0], sm1 = smax[1], sm2 = smax[2], sm3 = smax[3];
    int sm4 = smax[4], sm5 = smax[5], sm6 = smax[6];
    __syncthreads();

    int nvec   = n >> 2;
    int stride = (int)(gridDim.x * blockDim.x);
    int tid    = (int)(blockIdx.x * blockDim.x + threadIdx.x);

    const float4* __restrict__ xv = (const float4*)x;
    float4* __restrict__ ov = (float4*)out;

    for (int i = tid; i < nvec; i += stride) {
        float4 v = xv[i];
        float4 o;
        o.x = seg_one(v.x, s, os, sm0, sm1, sm2, sm3, sm4, sm5, sm6, tab);
        o.y = seg_one(v.y, s, os, sm0, sm1, sm2, sm3, sm4, sm5, sm6, tab);
        o.z = seg_one(v.z, s, os, sm0, sm1, sm2, sm3, sm4, sm5, sm6, tab);
        o.w = seg_one(v.w, s, os, sm0, sm1, sm2, sm3, sm4, sm5, sm6, tab);
        ov[i] = o;
    }
    // Scalar tail (n not divisible by 4 — not hit for this shape, kept safe).
    for (int i = (nvec << 2) + tid; i < n; i += stride) {
        out[i] = seg_one(x[i], s, os, sm0, sm1, sm2, sm3, sm4, sm5, sm6, tab);
    }
}

extern "C" void kernel_launch(void* const* d_in, const int* in_sizes, int n_in,
                              void* d_out, int out_size, void* d_ws, size_t ws_size,
                              hipStream_t stream) {
    const float* x           = (const float*)d_in[0];
    const float* input_scale = (const float*)d_in[1];
    const float* out_scale   = (const float*)d_in[2];
    const int*   alpha       = (const int*)d_in[3];
    const int*   beta        = (const int*)d_in[4];
    const int*   lsh         = (const int*)d_in[5];
    const int*   rsh         = (const int*)d_in[6];
    const int*   smax        = (const int*)d_in[7];
    float* out = (float*)d_out;

    int n = in_sizes[0];
    int nvec = n >> 2;
    int blocks = (nvec + 255) / 256;
    if (blocks > 2048) blocks = 2048;
    if (blocks < 1) blocks = 1;

    SegmentLUT_83021717831949_kernel<<<blocks, 256, 0, stream>>>(
        x, input_scale, out_scale, alpha, beta, lsh, rsh, smax, out, n);
}